// Round 1
// baseline (618.830 us; speedup 1.0000x reference)
//
#include <hip/hip_runtime.h>

#define VR_EPS 1e-10f
#define VR_S 128  // samples per ray (reference fixes n_samples=128)

// One 64-lane wave per ray; 2 samples per lane.
__global__ __launch_bounds__(256) void vr_kernel(
    const float* __restrict__ alpha,   // [R, 128]
    const float* __restrict__ rgbs,    // [R, 128, 3]
    float* __restrict__ out_rgb,       // [R, 3]
    float* __restrict__ out_w,         // [R, 128]
    int n_rays)
{
    const int wave_id = (blockIdx.x * blockDim.x + threadIdx.x) >> 6;
    const int lane    = threadIdx.x & 63;
    if (wave_id >= n_rays) return;
    const size_t ray = (size_t)wave_id;

    // ---- load 2 alphas per lane (coalesced float2 across the wave) ----
    const float2 a2 = *(const float2*)(alpha + ray * VR_S + 2 * lane);
    const float t0 = 1.0f - a2.x + VR_EPS;
    const float t1 = 1.0f - a2.y + VR_EPS;
    const float p  = t0 * t1;

    // ---- inclusive product-scan across 64 lanes ----
    float inc = p;
    #pragma unroll
    for (int off = 1; off < 64; off <<= 1) {
        float up = __shfl_up(inc, off, 64);
        inc *= (lane >= off) ? up : 1.0f;
    }
    // exclusive prefix (product of all lanes < this lane)
    float exc = __shfl_up(inc, 1, 64);
    if (lane == 0) exc = 1.0f;

    // trans for sample 2*lane is exc; for 2*lane+1 it's exc*t0
    const float w0 = exc * a2.x;
    const float w1 = exc * t0 * a2.y;

    // ---- weights out (coalesced float2) ----
    *(float2*)(out_w + ray * VR_S + 2 * lane) = make_float2(w0, w1);

    // ---- rgb accumulation ----
    const float* rp = rgbs + ray * (VR_S * 3) + 6 * lane;
    const float2 c01 = *(const float2*)(rp);      // s0.r, s0.g
    const float2 c23 = *(const float2*)(rp + 2);  // s0.b, s1.r
    const float2 c45 = *(const float2*)(rp + 4);  // s1.g, s1.b

    float r = w0 * c01.x + w1 * c23.y;
    float g = w0 * c01.y + w1 * c45.x;
    float b = w0 * c23.x + w1 * c45.y;

    // ---- wave reduction (sum across 64 lanes) ----
    #pragma unroll
    for (int off = 32; off > 0; off >>= 1) {
        r += __shfl_down(r, off, 64);
        g += __shfl_down(g, off, 64);
        b += __shfl_down(b, off, 64);
    }
    if (lane == 0) {
        float* op = out_rgb + ray * 3;
        op[0] = r; op[1] = g; op[2] = b;
    }
}

extern "C" void kernel_launch(void* const* d_in, const int* in_sizes, int n_in,
                              void* d_out, int out_size, void* d_ws, size_t ws_size,
                              hipStream_t stream) {
    const float* alpha = (const float*)d_in[0];
    const float* rgbs  = (const float*)d_in[1];
    const int n_rays = in_sizes[0] / VR_S;

    float* out_rgb = (float*)d_out;                       // first R*3 floats
    float* out_w   = (float*)d_out + (size_t)n_rays * 3;  // then R*128 floats

    // 4 rays per 256-thread block (one wave each)
    const int blocks = (n_rays + 3) / 4;
    vr_kernel<<<blocks, 256, 0, stream>>>(alpha, rgbs, out_rgb, out_w, n_rays);
}